// Round 5
// baseline (117.367 us; speedup 1.0000x reference)
//
#include <hip/hip_runtime.h>

// GNNComm: out[i,:] = mean_{j!=i} relu(concat(m_i,m_j)@W1^T + b1) @ W2^T + b2
// N=2048, D=8, H=64.
//
// relu(z) = (z+|z|)/2 =>
//   S[i,h] = 0.5*(N*a_ih + SX_h + C_ih), C_ih = sum_j |a_ih + x_jh|
//   a = X1[i]+b1, x = X2[j], SX = sum_j x_jh
// out[i,d] = 0.5*sum_h (C_ih + SX_h + N*a_ih - 2*relu(a_ih+x_ih)) W2[d,h]
//            / (N-1) + b2[d]
//
// R4 post-mortem: fusing prep into pair regressed (VGPR pressure from W1
// frags under the 128-cap + redundant staging). Reverted to R3's prep.
// R1-anchored accounting says pair3 ~ 22us vs ~7us VALU floor: TLP-starved
// (16 waves/CU) and LDS-heavy (17KB T-tile epilogue ~ 50 b128 reads/thread).
// This version: JCHUNKS=64 (grid 2048, 8KB LDS -> ~7 blocks/CU), register
// epilogue (W2 frags in regs + shfl_xor reduction over hq lanes + atomics
// from hq==0), chunk-SX folded into acc pre-projection (zero extra cost).

#define NN 2048
#define HH 64
#define DD 8

#define ITILES 32          // 32 i-tiles x 64 i
#define JCHUNKS 64         // 64 j-chunks x 32 j
#define JCHUNK (NN / JCHUNKS)
#define INV_SCALE (0.5f / (float)(NN - 1))

// --- K1: A[i,h] = X1[i,h]+b1[h]; X2[i,h]; zero out ---
__global__ void prep_kernel(const float* __restrict__ msg,
                            const float* __restrict__ W1,
                            const float* __restrict__ b1,
                            float* __restrict__ A,
                            float* __restrict__ X2,
                            float* __restrict__ out) {
    int idx = blockIdx.x * blockDim.x + threadIdx.x;  // 0 .. N*H-1
    if (idx < NN * DD) out[idx] = 0.f;                // zero the atomic target
    int i = idx >> 6;
    int h = idx & 63;
    const float4* m4 = (const float4*)(msg + i * DD);
    const float4* w4 = (const float4*)(W1 + h * (2 * DD));
    float4 m0 = m4[0], m1 = m4[1];
    float4 w0 = w4[0], w1 = w4[1], w2 = w4[2], w3 = w4[3];
    float x1 = m0.x * w0.x + m0.y * w0.y + m0.z * w0.z + m0.w * w0.w
             + m1.x * w1.x + m1.y * w1.y + m1.z * w1.z + m1.w * w1.w;
    float x2 = m0.x * w2.x + m0.y * w2.y + m0.z * w2.z + m0.w * w2.w
             + m1.x * w3.x + m1.y * w3.y + m1.z * w3.z + m1.w * w3.w;
    A[idx]  = x1 + b1[h];
    X2[idx] = x2;
}

// --- K2: pairwise |a+x| + register W2-projection + atomic scatter ---
// Block (it,jc): 64 i x 64 h x 32 j. Thread: hq=tid&15 (4 h's), il=tid>>4 (4 i's).
__global__ void __launch_bounds__(256, 6)
pair_fused(const float* __restrict__ A,
           const float* __restrict__ X2,
           const float* __restrict__ W2,
           const float* __restrict__ b2,
           float* __restrict__ out) {
    __shared__ float sX2f[JCHUNK * HH];   // 8 KB: [32 j][64 h]
    __shared__ float sSX[HH];             // chunk column sums

    int it = blockIdx.x & (ITILES - 1);
    int jc = blockIdx.x >> 5;             // 0..63
    int hq = threadIdx.x & 15;
    int il = threadIdx.x >> 4;
    int h0 = hq * 4;
    int i0 = it * 64 + il * 4;

    // stage X2 chunk: 512 float4, 2 per thread (coalesced)
    {
        const float4* src = (const float4*)(X2 + jc * JCHUNK * HH);
        float4* dst = (float4*)sX2f;
        dst[threadIdx.x]       = src[threadIdx.x];
        dst[threadIdx.x + 256] = src[threadIdx.x + 256];
    }

    float a[4][4];
#pragma unroll
    for (int k = 0; k < 4; ++k) {
        float4 av = *(const float4*)&A[(i0 + k) * HH + h0];
        a[k][0] = av.x; a[k][1] = av.y; a[k][2] = av.z; a[k][3] = av.w;
    }
    float acc[4][4];
#pragma unroll
    for (int k = 0; k < 4; ++k)
#pragma unroll
        for (int hh = 0; hh < 4; ++hh)
            acc[k][hh] = 0.f;

    __syncthreads();

    // ---- hot loop: 2 VALU/elem ----
    const float4* sX2v = (const float4*)sX2f;
#pragma unroll 4
    for (int j = 0; j < JCHUNK; ++j) {
        float4 x = sX2v[j * 16 + hq];
#pragma unroll
        for (int k = 0; k < 4; ++k) {
            acc[k][0] += __builtin_fabsf(a[k][0] + x.x);
            acc[k][1] += __builtin_fabsf(a[k][1] + x.y);
            acc[k][2] += __builtin_fabsf(a[k][2] + x.z);
            acc[k][3] += __builtin_fabsf(a[k][3] + x.w);
        }
    }

    // chunk column-sums (wave 0 only)
    if (threadIdx.x < 64) {
        float s0 = 0.f, s1 = 0.f, s2 = 0.f, s3 = 0.f;
#pragma unroll 4
        for (int j = 0; j < JCHUNK; j += 4) {
            s0 += sX2f[(j + 0) * HH + threadIdx.x];
            s1 += sX2f[(j + 1) * HH + threadIdx.x];
            s2 += sX2f[(j + 2) * HH + threadIdx.x];
            s3 += sX2f[(j + 3) * HH + threadIdx.x];
        }
        sSX[threadIdx.x] = (s0 + s1) + (s2 + s3);
    }
    __syncthreads();

    // diagonal fold: rows i==j live in block (it, jc==2*it + (il>>3))
    bool des = (jc == 2 * it + (il >> 3));
    if (des) {
        int jlb = (il & 7) * 4;  // local j of this thread's first i-row
#pragma unroll
        for (int k = 0; k < 4; ++k) {
            float4 xd = *(const float4*)&sX2f[(jlb + k) * HH + h0];
            float z0 = a[k][0] + xd.x, z1 = a[k][1] + xd.y;
            float z2 = a[k][2] + xd.z, z3 = a[k][3] + xd.w;
            acc[k][0] += (float)NN * a[k][0] - 2.f * (z0 > 0.f ? z0 : 0.f);
            acc[k][1] += (float)NN * a[k][1] - 2.f * (z1 > 0.f ? z1 : 0.f);
            acc[k][2] += (float)NN * a[k][2] - 2.f * (z2 > 0.f ? z2 : 0.f);
            acc[k][3] += (float)NN * a[k][3] - 2.f * (z3 > 0.f ? z3 : 0.f);
        }
    }

    // fold chunk-SX into acc (projects to the c_d term for free)
    {
        float4 sx = *(const float4*)&sSX[h0];
#pragma unroll
        for (int k = 0; k < 4; ++k) {
            acc[k][0] += sx.x; acc[k][1] += sx.y;
            acc[k][2] += sx.z; acc[k][3] += sx.w;
        }
    }

    // W2 fragment: this lane's 4 h-columns for all 8 d (L1-hot, 2KB array)
    float4 w[8];
    {
        const float4* w2v = (const float4*)W2;  // [8][16]
#pragma unroll
        for (int d = 0; d < 8; ++d)
            w[d] = w2v[d * 16 + hq];
    }

    // per i-row: project onto W2, reduce over hq lanes, atomic to out
#pragma unroll
    for (int k = 0; k < 4; ++k) {
        float p[8];
#pragma unroll
        for (int d = 0; d < 8; ++d)
            p[d] = acc[k][0] * w[d].x + acc[k][1] * w[d].y
                 + acc[k][2] * w[d].z + acc[k][3] * w[d].w;
#pragma unroll
        for (int m = 1; m < 16; m <<= 1)
#pragma unroll
            for (int d = 0; d < 8; ++d)
                p[d] += __shfl_xor(p[d], m);
        if (hq == 0) {
#pragma unroll
            for (int d = 0; d < 8; ++d) {
                float v = p[d] * INV_SCALE;
                if (des) v += b2[d];
                atomicAdd(&out[(i0 + k) * DD + d], v);
            }
        }
    }
}

extern "C" void kernel_launch(void* const* d_in, const int* in_sizes, int n_in,
                              void* d_out, int out_size, void* d_ws, size_t ws_size,
                              hipStream_t stream) {
    const float* msg = (const float*)d_in[0];  // [N, 8]
    const float* W1  = (const float*)d_in[1];  // [64, 16]
    const float* b1  = (const float*)d_in[2];  // [64]
    const float* W2  = (const float*)d_in[3];  // [8, 64]
    const float* b2  = (const float*)d_in[4];  // [8]
    float* out = (float*)d_out;                // [N, 8]

    float* ws = (float*)d_ws;
    float* A  = ws;            // N*H
    float* X2 = ws + NN * HH;  // N*H

    prep_kernel<<<(NN * HH) / 256, 256, 0, stream>>>(msg, W1, b1, A, X2, out);
    pair_fused<<<ITILES * JCHUNKS, 256, 0, stream>>>(A, X2, W2, b2, out);
}

// Round 6
// 85.881 us; speedup vs baseline: 1.3666x; 1.3666x over previous
//
#include <hip/hip_runtime.h>

// GNNComm: out[i,:] = mean_{j!=i} relu(concat(m_i,m_j)@W1^T + b1) @ W2^T + b2
// N=2048, D=8, H=64.
//
// relu(z) = (z+|z|)/2 =>
//   S[i,h] = 0.5*(N*a_ih + SX_h + C_ih), C_ih = sum_j |a_ih + x_jh|
//   a = X1[i]+b1, x = X2[j], SX = sum_j x_jh
// out[i,d] = 0.5*sum_h (C_ih + SX_h + N*a_ih - 2*relu(a_ih+x_ih)) W2[d,h]
//            / (N-1) + b2[d]
//
// R5 post-mortem: fp32 global atomics to out are the real bottleneck
// (WRITE_SIZE 32MB, ~32B HBM write-through per atomic, 64-way contention
// -> 58us). R1/R3/R5 all trace to this. This version has ZERO global
// atomics: pair blocks store per-chunk partials P[jc][i][d] with plain
// coalesced stores (2MB, proven cheap in R2), and a tiny reduce kernel
// sums the 32 chunks (+b2, *scale). Epilogue stays in registers
// (shfl-reduce over the 16 hq lanes; no 17KB T-tile).

#define NN 2048
#define HH 64
#define DD 8

#define ITILES 32          // 32 i-tiles x 64 i
#define JCHUNKS 32         // 32 j-chunks x 64 j
#define JCHUNK (NN / JCHUNKS)
#define INV_SCALE (0.5f / (float)(NN - 1))

// --- K1: A[i,h] = X1[i,h]+b1[h]; X2[i,h] ---
__global__ void prep_kernel(const float* __restrict__ msg,
                            const float* __restrict__ W1,
                            const float* __restrict__ b1,
                            float* __restrict__ A,
                            float* __restrict__ X2) {
    int idx = blockIdx.x * blockDim.x + threadIdx.x;  // 0 .. N*H-1
    int i = idx >> 6;
    int h = idx & 63;
    const float4* m4 = (const float4*)(msg + i * DD);
    const float4* w4 = (const float4*)(W1 + h * (2 * DD));
    float4 m0 = m4[0], m1 = m4[1];
    float4 w0 = w4[0], w1 = w4[1], w2 = w4[2], w3 = w4[3];
    float x1 = m0.x * w0.x + m0.y * w0.y + m0.z * w0.z + m0.w * w0.w
             + m1.x * w1.x + m1.y * w1.y + m1.z * w1.z + m1.w * w1.w;
    float x2 = m0.x * w2.x + m0.y * w2.y + m0.z * w2.z + m0.w * w2.w
             + m1.x * w3.x + m1.y * w3.y + m1.z * w3.z + m1.w * w3.w;
    A[idx]  = x1 + b1[h];
    X2[idx] = x2;
}

// --- K2: pairwise |a+x| + register W2-projection -> plain stores to P ---
// Block (it,jc): 64 i x 64 h x 64 j. Thread: hq=tid&15 (4 h's), il=tid>>4 (4 i's).
__global__ void __launch_bounds__(256, 4)
pair_kernel(const float* __restrict__ A,
            const float* __restrict__ X2,
            const float* __restrict__ W2,
            float* __restrict__ P) {
    __shared__ float sX2f[JCHUNK * HH];   // 16 KB: [64 j][64 h]
    __shared__ float sSX[HH];             // chunk column sums

    int it = blockIdx.x & (ITILES - 1);
    int jc = blockIdx.x >> 5;             // 0..31
    int hq = threadIdx.x & 15;
    int il = threadIdx.x >> 4;
    int h0 = hq * 4;
    int i0 = it * 64 + il * 4;
    bool des = (jc == it);                // diagonal block owns per-i terms

    // stage X2 chunk: 1024 float4, 4 per thread (coalesced)
    {
        const float4* src = (const float4*)(X2 + jc * JCHUNK * HH);
        float4* dst = (float4*)sX2f;
#pragma unroll
        for (int r = 0; r < 4; ++r)
            dst[threadIdx.x + r * 256] = src[threadIdx.x + r * 256];
    }

    float a[4][4];
#pragma unroll
    for (int k = 0; k < 4; ++k) {
        float4 av = *(const float4*)&A[(i0 + k) * HH + h0];
        a[k][0] = av.x; a[k][1] = av.y; a[k][2] = av.z; a[k][3] = av.w;
    }
    float acc[4][4];
#pragma unroll
    for (int k = 0; k < 4; ++k)
#pragma unroll
        for (int hh = 0; hh < 4; ++hh)
            acc[k][hh] = 0.f;

    __syncthreads();

    // ---- hot loop: 2 VALU/elem (add + add-with-|.|-modifier) ----
    const float4* sX2v = (const float4*)sX2f;
#pragma unroll 4
    for (int j = 0; j < JCHUNK; ++j) {
        float4 x = sX2v[j * 16 + hq];
#pragma unroll
        for (int k = 0; k < 4; ++k) {
            acc[k][0] += __builtin_fabsf(a[k][0] + x.x);
            acc[k][1] += __builtin_fabsf(a[k][1] + x.y);
            acc[k][2] += __builtin_fabsf(a[k][2] + x.z);
            acc[k][3] += __builtin_fabsf(a[k][3] + x.w);
        }
    }

    // chunk column-sums (wave 0 only; cheap, hidden by other waves)
    if (threadIdx.x < 64) {
        float s0 = 0.f, s1 = 0.f, s2 = 0.f, s3 = 0.f;
#pragma unroll 4
        for (int j = 0; j < JCHUNK; j += 4) {
            s0 += sX2f[(j + 0) * HH + threadIdx.x];
            s1 += sX2f[(j + 1) * HH + threadIdx.x];
            s2 += sX2f[(j + 2) * HH + threadIdx.x];
            s3 += sX2f[(j + 3) * HH + threadIdx.x];
        }
        sSX[threadIdx.x] = (s0 + s1) + (s2 + s3);
    }
    __syncthreads();

    // diagonal fold: local j == local i on the jc==it block
    if (des) {
        int jlb = il * 4;
#pragma unroll
        for (int k = 0; k < 4; ++k) {
            float4 xd = *(const float4*)&sX2f[(jlb + k) * HH + h0];
            float z0 = a[k][0] + xd.x, z1 = a[k][1] + xd.y;
            float z2 = a[k][2] + xd.z, z3 = a[k][3] + xd.w;
            acc[k][0] += (float)NN * a[k][0] - 2.f * (z0 > 0.f ? z0 : 0.f);
            acc[k][1] += (float)NN * a[k][1] - 2.f * (z1 > 0.f ? z1 : 0.f);
            acc[k][2] += (float)NN * a[k][2] - 2.f * (z2 > 0.f ? z2 : 0.f);
            acc[k][3] += (float)NN * a[k][3] - 2.f * (z3 > 0.f ? z3 : 0.f);
        }
    }

    // fold chunk-SX into acc (its W2-projection comes along for free)
    {
        float4 sx = *(const float4*)&sSX[h0];
#pragma unroll
        for (int k = 0; k < 4; ++k) {
            acc[k][0] += sx.x; acc[k][1] += sx.y;
            acc[k][2] += sx.z; acc[k][3] += sx.w;
        }
    }

    // W2 fragment: this lane's 4 h-columns for all 8 d (L1/L2-hot)
    float4 w[8];
    {
        const float4* w2v = (const float4*)W2;  // [8][16]
#pragma unroll
        for (int d = 0; d < 8; ++d)
            w[d] = w2v[d * 16 + hq];
    }

    // per i-row: project onto W2, shfl-reduce over hq lanes, plain store
#pragma unroll
    for (int k = 0; k < 4; ++k) {
        float p[8];
#pragma unroll
        for (int d = 0; d < 8; ++d)
            p[d] = acc[k][0] * w[d].x + acc[k][1] * w[d].y
                 + acc[k][2] * w[d].z + acc[k][3] * w[d].w;
#pragma unroll
        for (int m = 1; m < 16; m <<= 1)
#pragma unroll
            for (int d = 0; d < 8; ++d)
                p[d] += __shfl_xor(p[d], m);
        if (hq < 8) {
            // pv = p[hq] via unrolled select chain (keeps p[] in registers)
            float pv = p[0];
            pv = (hq == 1) ? p[1] : pv;
            pv = (hq == 2) ? p[2] : pv;
            pv = (hq == 3) ? p[3] : pv;
            pv = (hq == 4) ? p[4] : pv;
            pv = (hq == 5) ? p[5] : pv;
            pv = (hq == 6) ? p[6] : pv;
            pv = (hq == 7) ? p[7] : pv;
            P[(jc * NN + i0 + k) * DD + hq] = pv;
        }
    }
}

// --- K3: out[i,d] = INV_SCALE * sum_jc P[jc][i][d] + b2[d] ---
__global__ void reduce_kernel(const float* __restrict__ P,
                              const float* __restrict__ b2,
                              float* __restrict__ out) {
    int idx = blockIdx.x * blockDim.x + threadIdx.x;  // 0 .. N*D-1
    float s = 0.f;
#pragma unroll 8
    for (int jc = 0; jc < JCHUNKS; ++jc)
        s += P[jc * (NN * DD) + idx];   // coalesced across idx per jc
    out[idx] = s * INV_SCALE + b2[idx & 7];
}

extern "C" void kernel_launch(void* const* d_in, const int* in_sizes, int n_in,
                              void* d_out, int out_size, void* d_ws, size_t ws_size,
                              hipStream_t stream) {
    const float* msg = (const float*)d_in[0];  // [N, 8]
    const float* W1  = (const float*)d_in[1];  // [64, 16]
    const float* b1  = (const float*)d_in[2];  // [64]
    const float* W2  = (const float*)d_in[3];  // [8, 64]
    const float* b2  = (const float*)d_in[4];  // [8]
    float* out = (float*)d_out;                // [N, 8]

    float* ws = (float*)d_ws;
    float* A  = ws;                 // N*H floats
    float* X2 = ws + NN * HH;       // N*H floats
    float* P  = ws + 2 * NN * HH;   // JCHUNKS*N*D floats (2 MB)

    prep_kernel<<<(NN * HH) / 256, 256, 0, stream>>>(msg, W1, b1, A, X2);
    pair_kernel<<<ITILES * JCHUNKS, 256, 0, stream>>>(A, X2, W2, P);
    reduce_kernel<<<(NN * DD) / 256, 256, 0, stream>>>(P, b2, out);
}